// Round 3
// baseline (10340.627 us; speedup 1.0000x reference)
//
#include <hip/hip_runtime.h>
#include <hip/hip_bf16.h>
#include <math.h>

#define HID 64
#define ALPHA 0.5f

// ---------------- CSR build ----------------

__global__ void count_kernel(const int* __restrict__ dst, int* __restrict__ cnt, int E, int N) {
    int e = blockIdx.x * blockDim.x + threadIdx.x;
    if (e < E) {
        int d = dst[e];
        if ((unsigned)d < (unsigned)N) atomicAdd(&cnt[d], 1);
    }
}

__global__ void dinv_kernel(const int* __restrict__ cnt, float* __restrict__ dinv, int n) {
    int i = blockIdx.x * blockDim.x + threadIdx.x;
    if (i < n) {
        float deg = (float)(cnt[i] + 1);   // +1 self loop
        dinv[i] = rsqrtf(deg);
    }
}

__global__ void scan_kernel(const int* __restrict__ cnt, int* __restrict__ offs, int n) {
    __shared__ int buf[1024];
    __shared__ int carry_s;
    int tid = threadIdx.x;
    if (tid == 0) carry_s = 0;
    __syncthreads();
    for (int base = 0; base < n; base += 1024) {
        int i = base + tid;
        int v = (i < n) ? cnt[i] : 0;
        buf[tid] = v;
        __syncthreads();
        for (int off = 1; off < 1024; off <<= 1) {
            int t = (tid >= off) ? buf[tid - off] : 0;
            __syncthreads();
            buf[tid] += t;
            __syncthreads();
        }
        int carry = carry_s;
        if (i < n) offs[i] = carry + buf[tid] - v;  // exclusive
        int total = buf[1023];
        __syncthreads();
        if (tid == 0) carry_s = carry + total;
        __syncthreads();
    }
    if (tid == 0) offs[n] = carry_s;
}

__global__ void fill_kernel(const int* __restrict__ src, const int* __restrict__ dst,
                            const int* __restrict__ offs, int* __restrict__ cursor,
                            const float* __restrict__ dinv,
                            int* __restrict__ csr_src, float* __restrict__ csr_norm,
                            int E, int N) {
    int e = blockIdx.x * blockDim.x + threadIdx.x;
    if (e < E) {
        int s = src[e], d = dst[e];
        if ((unsigned)s < (unsigned)N && (unsigned)d < (unsigned)N) {
            int pos = atomicAdd(&cursor[d], 1);
            int j = offs[d] + pos;
            if ((unsigned)j < (unsigned)E) {
                csr_src[j] = s;
                csr_norm[j] = dinv[s] * dinv[d];
            }
        }
    }
}

// ---------------- lin1: h0 = relu(x @ W1 + b1), [n,512]@[512,64] ----------------

__global__ __launch_bounds__(256) void lin1_kernel(const float* __restrict__ x,
        const float* __restrict__ W, const float* __restrict__ b,
        float* __restrict__ out, int n) {
    const int BM = 64, BK = 32;
    __shared__ float As[BM][BK + 1];
    __shared__ float Ws[BK][64];
    int tid = threadIdx.x;
    int row0 = blockIdx.x * BM;
    int tx = tid & 15, ty = tid >> 4;   // 16 x 16, each thread 4x4 micro-tile
    float acc[4][4] = {};

    for (int k0 = 0; k0 < 512; k0 += BK) {
        {
            int r = tid >> 3;       // 0..31
            int c4 = tid & 7;       // 0..7
            #pragma unroll
            for (int rr = 0; rr < 2; rr++) {
                int row = row0 + r + rr * 32;
                float4 v = make_float4(0.f, 0.f, 0.f, 0.f);
                if (row < n) v = *(const float4*)&x[(size_t)row * 512 + k0 + c4 * 4];
                As[r + rr * 32][c4 * 4 + 0] = v.x;
                As[r + rr * 32][c4 * 4 + 1] = v.y;
                As[r + rr * 32][c4 * 4 + 2] = v.z;
                As[r + rr * 32][c4 * 4 + 3] = v.w;
            }
        }
        {
            int r = tid >> 4;       // 0..15
            int c4 = tid & 15;      // 0..15
            #pragma unroll
            for (int rr = 0; rr < 2; rr++) {
                float4 v = *(const float4*)&W[(size_t)(k0 + r + rr * 16) * 64 + c4 * 4];
                *(float4*)&Ws[r + rr * 16][c4 * 4] = v;
            }
        }
        __syncthreads();
        #pragma unroll
        for (int kk = 0; kk < BK; kk++) {
            float a0 = As[ty * 4 + 0][kk];
            float a1 = As[ty * 4 + 1][kk];
            float a2 = As[ty * 4 + 2][kk];
            float a3 = As[ty * 4 + 3][kk];
            float4 w = *(float4*)&Ws[kk][tx * 4];
            acc[0][0] += a0 * w.x; acc[0][1] += a0 * w.y; acc[0][2] += a0 * w.z; acc[0][3] += a0 * w.w;
            acc[1][0] += a1 * w.x; acc[1][1] += a1 * w.y; acc[1][2] += a1 * w.z; acc[1][3] += a1 * w.w;
            acc[2][0] += a2 * w.x; acc[2][1] += a2 * w.y; acc[2][2] += a2 * w.z; acc[2][3] += a2 * w.w;
            acc[3][0] += a3 * w.x; acc[3][1] += a3 * w.y; acc[3][2] += a3 * w.z; acc[3][3] += a3 * w.w;
        }
        __syncthreads();
    }
    #pragma unroll
    for (int i = 0; i < 4; i++) {
        int row = row0 + ty * 4 + i;
        if (row < n) {
            #pragma unroll
            for (int j = 0; j < 4; j++) {
                int col = tx * 4 + j;
                float v = acc[i][j] + b[col];
                out[(size_t)row * 64 + col] = fmaxf(v, 0.f);
            }
        }
    }
}

// ---------------- fused GCNII layer ----------------

__global__ __launch_bounds__(256) void layer_kernel(
        const float* __restrict__ h_in, const float* __restrict__ x0,
        float* __restrict__ h_out,
        const int* __restrict__ rowptr, const int* __restrict__ csr_src,
        const float* __restrict__ csr_norm, const float* __restrict__ dinv,
        const float* __restrict__ W, float beta, int n) {
    __shared__ float Wsh[HID * HID];          // 16 KB
    alignas(16) __shared__ float zs[4][HID];  // one row per wave
    int tid = threadIdx.x;
    for (int i = tid; i < HID * HID / 4; i += 256)
        ((float4*)Wsh)[i] = ((const float4*)W)[i];
    __syncthreads();
    int lane = tid & 63, wave = tid >> 6;
    float wc[HID];
    #pragma unroll
    for (int k = 0; k < HID; k++) wc[k] = Wsh[k * HID + lane];

    float omb = 1.0f - beta;
    int nwaves = gridDim.x * 4;
    for (int i = blockIdx.x * 4 + wave; i < n; i += nwaves) {
        float di = dinv[i];
        size_t rowb = (size_t)i * HID;
        float acc = di * di * h_in[rowb + lane];          // self-loop
        int e0 = rowptr[i], e1 = rowptr[i + 1];
        if (e0 < 0) e0 = 0;
        if (e1 > rowptr[n]) e1 = rowptr[n];
        for (int e = e0; e < e1; e++) {
            int s = csr_src[e];
            if ((unsigned)s < (unsigned)n) {
                float nv = csr_norm[e];
                acc += nv * h_in[(size_t)s * HID + lane];
            }
        }
        float z = 0.5f * acc + 0.5f * x0[rowb + lane];    // ALPHA = 0.5
        zs[wave][lane] = z;                               // in-wave LDS broadcast
        float mv = 0.f;
        #pragma unroll
        for (int k4 = 0; k4 < 16; k4++) {
            float4 zb = *(float4*)&zs[wave][k4 * 4];
            mv += zb.x * wc[k4 * 4 + 0] + zb.y * wc[k4 * 4 + 1]
                + zb.z * wc[k4 * 4 + 2] + zb.w * wc[k4 * 4 + 3];
        }
        float y = omb * z + beta * mv;
        h_out[rowb + lane] = fmaxf(y, 0.f);
    }
}

// ---------------- lin2 + log_softmax ----------------

__global__ __launch_bounds__(256) void out_kernel(const float* __restrict__ h,
        const float* __restrict__ W2, const float* __restrict__ b2,
        float* __restrict__ out, int n) {
    __shared__ float W2s[64 * 40];
    alignas(16) __shared__ float hs[4][64];
    int tid = threadIdx.x;
    for (int i = tid; i < 64 * 40; i += 256) W2s[i] = W2[i];
    __syncthreads();
    int lane = tid & 63, wave = tid >> 6;
    int c = (lane < 40) ? lane : 0;
    float wc[64];
    #pragma unroll
    for (int k = 0; k < 64; k++) wc[k] = W2s[k * 40 + c];
    float bias = b2[c];
    for (int i = blockIdx.x * 4 + wave; i < n; i += gridDim.x * 4) {
        hs[wave][lane] = h[(size_t)i * 64 + lane];
        float o = bias;
        #pragma unroll
        for (int k4 = 0; k4 < 16; k4++) {
            float4 hb = *(float4*)&hs[wave][k4 * 4];
            o += hb.x * wc[k4 * 4 + 0] + hb.y * wc[k4 * 4 + 1]
               + hb.z * wc[k4 * 4 + 2] + hb.w * wc[k4 * 4 + 3];
        }
        float val = (lane < 40) ? o : -INFINITY;
        float m = val;
        #pragma unroll
        for (int d = 1; d < 64; d <<= 1) m = fmaxf(m, __shfl_xor(m, d, 64));
        float e = (lane < 40) ? expf(o - m) : 0.f;
        float s = e;
        #pragma unroll
        for (int d = 1; d < 64; d <<= 1) s += __shfl_xor(s, d, 64);
        if (lane < 40) out[(size_t)i * 40 + lane] = (o - m) - logf(s);
    }
}

__global__ void zero_out_kernel(float* __restrict__ out, int n) {
    int i = blockIdx.x * blockDim.x + threadIdx.x;
    if (i < n) out[i] = 0.f;
}

// ---------------- launcher ----------------

extern "C" void kernel_launch(void* const* d_in, const int* in_sizes, int n_in,
                              void* d_out, int out_size, void* d_ws, size_t ws_size,
                              hipStream_t stream) {
    const float* x    = (const float*)d_in[0];
    const int*   ei   = (const int*)d_in[1];     // int32 (harness converts ints to int32)
    const float* W1   = (const float*)d_in[2];
    const float* b1   = (const float*)d_in[3];
    const float* Wc   = (const float*)d_in[4];
    const float* W2   = (const float*)d_in[5];
    const float* b2   = (const float*)d_in[6];
    float* outp = (float*)d_out;

    const int N = in_sizes[0] / 512;         // 50000
    const int E = in_sizes[1] / 2;           // 800000
    const int L = in_sizes[4] / (HID * HID); // 64

    const int* src = ei;
    const int* dst = ei + E;

    // workspace carve-up (all 4-byte elems) — total ≈ 46 MB
    size_t need = ((size_t)N * HID * 3 + (size_t)N * 3 + (N + 1) + (size_t)E * 2) * 4;
    if (ws_size < need) {
        // diagnosable failure mode instead of OOB crash
        zero_out_kernel<<<(out_size + 255) / 256, 256, 0, stream>>>(outp, out_size);
        return;
    }
    char* p = (char*)d_ws;
    float* hA   = (float*)p;            p += (size_t)N * HID * 4;
    float* hB   = (float*)p;            p += (size_t)N * HID * 4;
    float* x0b  = (float*)p;            p += (size_t)N * HID * 4;
    float* dinv = (float*)p;            p += (size_t)N * 4;
    float* csr_norm = (float*)p;        p += (size_t)E * 4;
    int*   cnt  = (int*)p;              p += (size_t)N * 4;
    int*   offs = (int*)p;              p += (size_t)(N + 1) * 4;
    int*   cursor = (int*)p;            p += (size_t)N * 4;
    int*   csr_src = (int*)p;           p += (size_t)E * 4;

    hipMemsetAsync(cnt, 0, (size_t)N * 4, stream);
    hipMemsetAsync(cursor, 0, (size_t)N * 4, stream);

    count_kernel<<<(E + 255) / 256, 256, 0, stream>>>(dst, cnt, E, N);
    dinv_kernel<<<(N + 255) / 256, 256, 0, stream>>>(cnt, dinv, N);
    scan_kernel<<<1, 1024, 0, stream>>>(cnt, offs, N);
    fill_kernel<<<(E + 255) / 256, 256, 0, stream>>>(src, dst, offs, cursor, dinv,
                                                     csr_src, csr_norm, E, N);

    lin1_kernel<<<(N + 63) / 64, 256, 0, stream>>>(x, W1, b1, x0b, N);

    float* cur_in = x0b;
    float* cur_out = hA;
    for (int l = 0; l < L; l++) {
        float beta = log1pf(1.0f / (float)(l + 1));
        layer_kernel<<<2048, 256, 0, stream>>>(cur_in, x0b, cur_out, offs, csr_src,
                                               csr_norm, dinv, Wc + (size_t)l * HID * HID,
                                               beta, N);
        float* nxt = (cur_out == hA) ? hB : hA;
        cur_in = cur_out;
        cur_out = nxt;
    }

    out_kernel<<<1024, 256, 0, stream>>>(cur_in, W2, b2, outp, N);
}

// Round 4
// 3585.814 us; speedup vs baseline: 2.8838x; 2.8838x over previous
//
#include <hip/hip_runtime.h>
#include <hip/hip_bf16.h>
#include <math.h>

#define HID 64

// ---------------- CSR build ----------------

__global__ void count_kernel(const int* __restrict__ dst, int* __restrict__ cnt, int E, int N) {
    int e = blockIdx.x * blockDim.x + threadIdx.x;
    if (e < E) {
        int d = dst[e];
        if ((unsigned)d < (unsigned)N) atomicAdd(&cnt[d], 1);
    }
}

__global__ void dinv_kernel(const int* __restrict__ cnt, float* __restrict__ dinv, int n) {
    int i = blockIdx.x * blockDim.x + threadIdx.x;
    if (i < n) {
        float deg = (float)(cnt[i] + 1);   // +1 self loop
        dinv[i] = rsqrtf(deg);
    }
}

__global__ void scan_kernel(const int* __restrict__ cnt, int* __restrict__ offs, int n) {
    __shared__ int buf[1024];
    __shared__ int carry_s;
    int tid = threadIdx.x;
    if (tid == 0) carry_s = 0;
    __syncthreads();
    for (int base = 0; base < n; base += 1024) {
        int i = base + tid;
        int v = (i < n) ? cnt[i] : 0;
        buf[tid] = v;
        __syncthreads();
        for (int off = 1; off < 1024; off <<= 1) {
            int t = (tid >= off) ? buf[tid - off] : 0;
            __syncthreads();
            buf[tid] += t;
            __syncthreads();
        }
        int carry = carry_s;
        if (i < n) offs[i] = carry + buf[tid] - v;  // exclusive
        int total = buf[1023];
        __syncthreads();
        if (tid == 0) carry_s = carry + total;
        __syncthreads();
    }
    if (tid == 0) offs[n] = carry_s;
}

// packed edge record: {src, norm}
__global__ void fill_kernel(const int* __restrict__ src, const int* __restrict__ dst,
                            const int* __restrict__ offs, int* __restrict__ cursor,
                            const float* __restrict__ dinv,
                            int2* __restrict__ pack, int E, int N) {
    int e = blockIdx.x * blockDim.x + threadIdx.x;
    if (e < E) {
        int s = src[e], d = dst[e];
        if ((unsigned)s < (unsigned)N && (unsigned)d < (unsigned)N) {
            int pos = atomicAdd(&cursor[d], 1);
            int j = offs[d] + pos;
            if ((unsigned)j < (unsigned)E)
                pack[j] = make_int2(s, __float_as_int(dinv[s] * dinv[d]));
        }
    }
}

// ---------------- lin1: h0 = relu(x @ W1 + b1), [n,512]@[512,64] ----------------

__global__ __launch_bounds__(256) void lin1_kernel(const float* __restrict__ x,
        const float* __restrict__ W, const float* __restrict__ b,
        float* __restrict__ out, int n) {
    const int BM = 64, BK = 32;
    __shared__ float As[BM][BK + 1];
    __shared__ float Ws[BK][64];
    int tid = threadIdx.x;
    int row0 = blockIdx.x * BM;
    int tx = tid & 15, ty = tid >> 4;
    float acc[4][4] = {};

    for (int k0 = 0; k0 < 512; k0 += BK) {
        {
            int r = tid >> 3, c4 = tid & 7;
            #pragma unroll
            for (int rr = 0; rr < 2; rr++) {
                int row = row0 + r + rr * 32;
                float4 v = make_float4(0.f, 0.f, 0.f, 0.f);
                if (row < n) v = *(const float4*)&x[(size_t)row * 512 + k0 + c4 * 4];
                As[r + rr * 32][c4 * 4 + 0] = v.x;
                As[r + rr * 32][c4 * 4 + 1] = v.y;
                As[r + rr * 32][c4 * 4 + 2] = v.z;
                As[r + rr * 32][c4 * 4 + 3] = v.w;
            }
        }
        {
            int r = tid >> 4, c4 = tid & 15;
            #pragma unroll
            for (int rr = 0; rr < 2; rr++) {
                float4 v = *(const float4*)&W[(size_t)(k0 + r + rr * 16) * 64 + c4 * 4];
                *(float4*)&Ws[r + rr * 16][c4 * 4] = v;
            }
        }
        __syncthreads();
        #pragma unroll
        for (int kk = 0; kk < BK; kk++) {
            float a0 = As[ty * 4 + 0][kk];
            float a1 = As[ty * 4 + 1][kk];
            float a2 = As[ty * 4 + 2][kk];
            float a3 = As[ty * 4 + 3][kk];
            float4 w = *(float4*)&Ws[kk][tx * 4];
            acc[0][0] += a0 * w.x; acc[0][1] += a0 * w.y; acc[0][2] += a0 * w.z; acc[0][3] += a0 * w.w;
            acc[1][0] += a1 * w.x; acc[1][1] += a1 * w.y; acc[1][2] += a1 * w.z; acc[1][3] += a1 * w.w;
            acc[2][0] += a2 * w.x; acc[2][1] += a2 * w.y; acc[2][2] += a2 * w.z; acc[2][3] += a2 * w.w;
            acc[3][0] += a3 * w.x; acc[3][1] += a3 * w.y; acc[3][2] += a3 * w.z; acc[3][3] += a3 * w.w;
        }
        __syncthreads();
    }
    #pragma unroll
    for (int i = 0; i < 4; i++) {
        int row = row0 + ty * 4 + i;
        if (row < n) {
            #pragma unroll
            for (int j = 0; j < 4; j++) {
                int col = tx * 4 + j;
                float v = acc[i][j] + b[col];
                out[(size_t)row * 64 + col] = fmaxf(v, 0.f);
            }
        }
    }
}

// ---------------- fused GCNII layer ----------------
// 4 waves/block, 4 nodes/wave (4 lane-groups x 16 lanes, float4 per lane).
// Phase 1: edge gather with 4x unroll  -> ~16 outstanding row gathers per wave.
// Phase 2: per node (lane=feature): z = 0.5*agg + 0.5*x0; y=(1-b)z + b*(z@W); relu.

__global__ __launch_bounds__(256) void layer_kernel(
        const float4* __restrict__ h4, const float* __restrict__ x0,
        float* __restrict__ h_out,
        const int* __restrict__ rowptr, const int2* __restrict__ pack,
        const float* __restrict__ dinv,
        const float* __restrict__ W, float beta, int n) {
    __shared__ float Wsh[HID * HID];                 // 16 KB
    alignas(16) __shared__ float aggs[4][4][HID];    // 4 KB
    alignas(16) __shared__ float zs[4][HID];         // 1 KB
    int tid = threadIdx.x;
    for (int i = tid; i < HID * HID / 4; i += 256)
        ((float4*)Wsh)[i] = ((const float4*)W)[i];
    __syncthreads();
    int lane = tid & 63, wave = tid >> 6;
    float wc[HID];
    #pragma unroll
    for (int k = 0; k < HID; k++) wc[k] = Wsh[k * HID + lane];

    int g = lane >> 4;        // lane-group = node within wave
    int c = lane & 15;        // float4 slot within row
    float omb = 1.0f - beta;

    for (int base = (blockIdx.x * 4 + wave) * 4; base < n; base += gridDim.x * 16) {
        // ---- phase 1: gather (group g owns node base+g) ----
        int node = base + g;
        float4 acc;
        if (node < n) {
            float di = dinv[node];
            float d2 = di * di;
            acc = h4[(size_t)node * 16 + c];          // self loop
            acc.x *= d2; acc.y *= d2; acc.z *= d2; acc.w *= d2;
            int e0 = rowptr[node];
            int deg = rowptr[node + 1] - e0;
            int e = 0;
            for (; e + 4 <= deg; e += 4) {            // 4 independent gathers in flight
                int2 p0 = pack[e0 + e + 0];
                int2 p1 = pack[e0 + e + 1];
                int2 p2 = pack[e0 + e + 2];
                int2 p3 = pack[e0 + e + 3];
                float4 v0 = h4[(size_t)p0.x * 16 + c];
                float4 v1 = h4[(size_t)p1.x * 16 + c];
                float4 v2 = h4[(size_t)p2.x * 16 + c];
                float4 v3 = h4[(size_t)p3.x * 16 + c];
                float n0 = __int_as_float(p0.y), n1 = __int_as_float(p1.y);
                float n2 = __int_as_float(p2.y), n3 = __int_as_float(p3.y);
                acc.x += n0 * v0.x + n1 * v1.x + n2 * v2.x + n3 * v3.x;
                acc.y += n0 * v0.y + n1 * v1.y + n2 * v2.y + n3 * v3.y;
                acc.z += n0 * v0.z + n1 * v1.z + n2 * v2.z + n3 * v3.z;
                acc.w += n0 * v0.w + n1 * v1.w + n2 * v2.w + n3 * v3.w;
            }
            for (; e < deg; e++) {
                int2 p = pack[e0 + e];
                float4 v = h4[(size_t)p.x * 16 + c];
                float nv = __int_as_float(p.y);
                acc.x += nv * v.x; acc.y += nv * v.y;
                acc.z += nv * v.z; acc.w += nv * v.w;
            }
        } else {
            acc = make_float4(0.f, 0.f, 0.f, 0.f);
        }
        *(float4*)&aggs[wave][g][c * 4] = acc;        // wave-internal transpose (DS in-order)

        // ---- phase 2: per node, lane = feature ----
        #pragma unroll
        for (int nn = 0; nn < 4; nn++) {
            int row = base + nn;
            if (row >= n) break;
            float agg = aggs[wave][nn][lane];
            float z = 0.5f * agg + 0.5f * x0[(size_t)row * HID + lane];  // ALPHA=0.5
            zs[wave][lane] = z;
            float mv = 0.f;
            #pragma unroll
            for (int k4 = 0; k4 < 16; k4++) {
                float4 zb = *(float4*)&zs[wave][k4 * 4];
                mv += zb.x * wc[k4 * 4 + 0] + zb.y * wc[k4 * 4 + 1]
                    + zb.z * wc[k4 * 4 + 2] + zb.w * wc[k4 * 4 + 3];
            }
            h_out[(size_t)row * HID + lane] = fmaxf(omb * z + beta * mv, 0.f);
        }
    }
}

// ---------------- lin2 + log_softmax ----------------

__global__ __launch_bounds__(256) void out_kernel(const float* __restrict__ h,
        const float* __restrict__ W2, const float* __restrict__ b2,
        float* __restrict__ out, int n) {
    __shared__ float W2s[64 * 40];
    alignas(16) __shared__ float hs[4][64];
    int tid = threadIdx.x;
    for (int i = tid; i < 64 * 40; i += 256) W2s[i] = W2[i];
    __syncthreads();
    int lane = tid & 63, wave = tid >> 6;
    int c = (lane < 40) ? lane : 0;
    float wc[64];
    #pragma unroll
    for (int k = 0; k < 64; k++) wc[k] = W2s[k * 40 + c];
    float bias = b2[c];
    for (int i = blockIdx.x * 4 + wave; i < n; i += gridDim.x * 4) {
        hs[wave][lane] = h[(size_t)i * 64 + lane];
        float o = bias;
        #pragma unroll
        for (int k4 = 0; k4 < 16; k4++) {
            float4 hb = *(float4*)&hs[wave][k4 * 4];
            o += hb.x * wc[k4 * 4 + 0] + hb.y * wc[k4 * 4 + 1]
               + hb.z * wc[k4 * 4 + 2] + hb.w * wc[k4 * 4 + 3];
        }
        float val = (lane < 40) ? o : -INFINITY;
        float m = val;
        #pragma unroll
        for (int d = 1; d < 64; d <<= 1) m = fmaxf(m, __shfl_xor(m, d, 64));
        float e = (lane < 40) ? expf(o - m) : 0.f;
        float s = e;
        #pragma unroll
        for (int d = 1; d < 64; d <<= 1) s += __shfl_xor(s, d, 64);
        if (lane < 40) out[(size_t)i * 40 + lane] = (o - m) - logf(s);
    }
}

__global__ void zero_out_kernel(float* __restrict__ out, int n) {
    int i = blockIdx.x * blockDim.x + threadIdx.x;
    if (i < n) out[i] = 0.f;
}

// ---------------- launcher ----------------

extern "C" void kernel_launch(void* const* d_in, const int* in_sizes, int n_in,
                              void* d_out, int out_size, void* d_ws, size_t ws_size,
                              hipStream_t stream) {
    const float* x    = (const float*)d_in[0];
    const int*   ei   = (const int*)d_in[1];     // int32
    const float* W1   = (const float*)d_in[2];
    const float* b1   = (const float*)d_in[3];
    const float* Wc   = (const float*)d_in[4];
    const float* W2   = (const float*)d_in[5];
    const float* b2   = (const float*)d_in[6];
    float* outp = (float*)d_out;

    const int N = in_sizes[0] / 512;         // 50000
    const int E = in_sizes[1] / 2;           // 800000
    const int L = in_sizes[4] / (HID * HID); // 64

    const int* src = ei;
    const int* dst = ei + E;

    size_t need = ((size_t)N * HID * 3 + (size_t)N * 3 + (N + 1)) * 4 + (size_t)E * 8;
    if (ws_size < need) {
        zero_out_kernel<<<(out_size + 255) / 256, 256, 0, stream>>>(outp, out_size);
        return;
    }
    char* p = (char*)d_ws;
    float* hA   = (float*)p;            p += (size_t)N * HID * 4;
    float* hB   = (float*)p;            p += (size_t)N * HID * 4;
    float* x0b  = (float*)p;            p += (size_t)N * HID * 4;
    float* dinv = (float*)p;            p += (size_t)N * 4;
    int2*  pack = (int2*)p;             p += (size_t)E * 8;
    int*   cnt  = (int*)p;              p += (size_t)N * 4;
    int*   offs = (int*)p;              p += (size_t)(N + 1) * 4;
    int*   cursor = (int*)p;            p += (size_t)N * 4;

    hipMemsetAsync(cnt, 0, (size_t)N * 4, stream);
    hipMemsetAsync(cursor, 0, (size_t)N * 4, stream);

    count_kernel<<<(E + 255) / 256, 256, 0, stream>>>(dst, cnt, E, N);
    dinv_kernel<<<(N + 255) / 256, 256, 0, stream>>>(cnt, dinv, N);
    scan_kernel<<<1, 1024, 0, stream>>>(cnt, offs, N);
    fill_kernel<<<(E + 255) / 256, 256, 0, stream>>>(src, dst, offs, cursor, dinv,
                                                     pack, E, N);

    lin1_kernel<<<(N + 63) / 64, 256, 0, stream>>>(x, W1, b1, x0b, N);

    // 16 nodes per block -> 3125 blocks covers N=50000 exactly
    int nblocks = (N + 15) / 16;
    float* cur_in = x0b;
    float* cur_out = hA;
    for (int l = 0; l < L; l++) {
        float beta = log1pf(1.0f / (float)(l + 1));
        layer_kernel<<<nblocks, 256, 0, stream>>>((const float4*)cur_in, x0b, cur_out,
                                                  offs, pack, dinv,
                                                  Wc + (size_t)l * HID * HID, beta, N);
        float* nxt = (cur_out == hA) ? hB : hA;
        cur_in = cur_out;
        cur_out = nxt;
    }

    out_kernel<<<1024, 256, 0, stream>>>(cur_in, W2, b2, outp, N);
}